// Round 1
// baseline (7354.070 us; speedup 1.0000x reference)
//
#include <hip/hip_runtime.h>
#include <cstdint>
#include <cstddef>

#define NEGV -1000000000.0f

// ---------- fast device math (fp32, ~1e-7 abs error — argmax-safe) ----------
__device__ __forceinline__ float fsigm(float x) {
  return 1.0f / (1.0f + __expf(-x));
}
__device__ __forceinline__ float ftanh(float x) {
  x = fminf(x, 30.0f);                 // avoid inf/inf; exp(60) finite
  const float e = __expf(2.0f * x);
  return (e - 1.0f) / (e + 1.0f);
}

// ---------------------------------------------------------------------------
// Generic fp32 GEMM: C[M,N] = concat(A0[:,0:K0], A1[:,0:K1]) @ W[N,K]^T + bias
// permuteBL: A row m=(b*64+l) is read from physical row (l*512+b) (context layout)
// BM=BN=64, BK=16, 256 threads, 4x4 micro-tile.
// ---------------------------------------------------------------------------
__global__ __launch_bounds__(256) void gemm_bias_k(
    const float* __restrict__ A0, const float* __restrict__ A1,
    const float* __restrict__ W, const float* __restrict__ bias,
    float* __restrict__ C, int M, int N, int K, int K0, int K1, int permuteBL)
{
  __shared__ float As[16][68];
  __shared__ float Ws[16][68];
  const int bn = blockIdx.x << 6;
  const int bm = blockIdx.y << 6;
  const int t  = threadIdx.x;
  const int ty = t >> 4, tx = t & 15;
  const int lr = t >> 2, lk = (t & 3) << 2;
  const int m  = bm + lr;
  const size_t arow = permuteBL ? (size_t)(((m & 63) << 9) | (m >> 6)) : (size_t)m;
  const float* wrow = W + (size_t)(bn + lr) * K;
  float acc[4][4] = {};
  for (int k0 = 0; k0 < K; k0 += 16) {
    const int kk = k0 + lk;
    float4 av;
    if (kk < K0) av = *(const float4*)(A0 + arow * (size_t)K0 + kk);
    else         av = *(const float4*)(A1 + (size_t)m * K1 + (kk - K0));
    const float4 wv = *(const float4*)(wrow + kk);
    As[lk + 0][lr] = av.x; As[lk + 1][lr] = av.y; As[lk + 2][lr] = av.z; As[lk + 3][lr] = av.w;
    Ws[lk + 0][lr] = wv.x; Ws[lk + 1][lr] = wv.y; Ws[lk + 2][lr] = wv.z; Ws[lk + 3][lr] = wv.w;
    __syncthreads();
#pragma unroll
    for (int k = 0; k < 16; ++k) {
      const float4 a = *(const float4*)&As[k][ty << 2];
      const float4 w = *(const float4*)&Ws[k][tx << 2];
      acc[0][0] += a.x * w.x; acc[0][1] += a.x * w.y; acc[0][2] += a.x * w.z; acc[0][3] += a.x * w.w;
      acc[1][0] += a.y * w.x; acc[1][1] += a.y * w.y; acc[1][2] += a.y * w.z; acc[1][3] += a.y * w.w;
      acc[2][0] += a.z * w.x; acc[2][1] += a.z * w.y; acc[2][2] += a.z * w.z; acc[2][3] += a.z * w.w;
      acc[3][0] += a.w * w.x; acc[3][1] += a.w * w.y; acc[3][2] += a.w * w.z; acc[3][3] += a.w * w.w;
    }
    __syncthreads();
  }
  const float4 bv = *(const float4*)(bias + bn + (tx << 2));
#pragma unroll
  for (int i = 0; i < 4; ++i) {
    float4 o;
    o.x = acc[i][0] + bv.x; o.y = acc[i][1] + bv.y;
    o.z = acc[i][2] + bv.z; o.w = acc[i][3] + bv.w;
    *(float4*)(C + (size_t)(bm + (ty << 2) + i) * N + bn + (tx << 2)) = o;
  }
}

// ---------------------------------------------------------------------------
// gates GEMM (M=512, N=1024 interleaved i,f,g,o per unit, K=512 = [x|h])
// + fused LSTM pointwise epilogue writing h_next, c_next. No gates buffer.
// ---------------------------------------------------------------------------
__global__ __launch_bounds__(256) void gates_lstm_k(
    const float* __restrict__ x, const float* __restrict__ hin,
    const float* __restrict__ Wcat, const float* __restrict__ bcat,
    const float* __restrict__ cin, float* __restrict__ cnew,
    float* __restrict__ hnew)
{
  __shared__ float As[16][68];
  __shared__ float Ws[16][68];
  const int bn = blockIdx.x << 6;
  const int bm = blockIdx.y << 6;
  const int t  = threadIdx.x;
  const int ty = t >> 4, tx = t & 15;
  const int lr = t >> 2, lk = (t & 3) << 2;
  const int m  = bm + lr;
  const float* wrow = Wcat + ((size_t)(bn + lr) << 9);
  float acc[4][4] = {};
  for (int k0 = 0; k0 < 512; k0 += 16) {
    const int kk = k0 + lk;
    float4 av;
    if (kk < 256) av = *(const float4*)(x   + ((size_t)m << 8) + kk);
    else          av = *(const float4*)(hin + ((size_t)m << 8) + (kk - 256));
    const float4 wv = *(const float4*)(wrow + kk);
    As[lk + 0][lr] = av.x; As[lk + 1][lr] = av.y; As[lk + 2][lr] = av.z; As[lk + 3][lr] = av.w;
    Ws[lk + 0][lr] = wv.x; Ws[lk + 1][lr] = wv.y; Ws[lk + 2][lr] = wv.z; Ws[lk + 3][lr] = wv.w;
    __syncthreads();
#pragma unroll
    for (int k = 0; k < 16; ++k) {
      const float4 a = *(const float4*)&As[k][ty << 2];
      const float4 w = *(const float4*)&Ws[k][tx << 2];
      acc[0][0] += a.x * w.x; acc[0][1] += a.x * w.y; acc[0][2] += a.x * w.z; acc[0][3] += a.x * w.w;
      acc[1][0] += a.y * w.x; acc[1][1] += a.y * w.y; acc[1][2] += a.y * w.z; acc[1][3] += a.y * w.w;
      acc[2][0] += a.z * w.x; acc[2][1] += a.z * w.y; acc[2][2] += a.z * w.z; acc[2][3] += a.z * w.w;
      acc[3][0] += a.w * w.x; acc[3][1] += a.w * w.y; acc[3][2] += a.w * w.z; acc[3][3] += a.w * w.w;
    }
    __syncthreads();
  }
  // epilogue: thread's 4 consecutive cols = (i,f,g,o) of hidden unit jc
  const int jc = (bn >> 2) + tx;
  const float4 bb = *(const float4*)(bcat + bn + (tx << 2));
#pragma unroll
  for (int i = 0; i < 4; ++i) {
    const int mm = bm + (ty << 2) + i;
    const float ig = fsigm(acc[i][0] + bb.x);
    const float fg = fsigm(acc[i][1] + bb.y);
    const float gg = ftanh(acc[i][2] + bb.z);
    const float og = fsigm(acc[i][3] + bb.w);
    const float c  = fg * cin[(mm << 8) + jc] + ig * gg;
    const float h  = og * ftanh(c);
    cnew[(mm << 8) + jc] = c;
    hnew[(mm << 8) + jc] = h;
  }
}

// ---------------------------------------------------------------------------
// attention-g: mask update, scores over e_g, softmax, context. 1 block per b.
// ---------------------------------------------------------------------------
__global__ __launch_bounds__(256) void attn_g_k(
    const float* __restrict__ qg, const float* __restrict__ e2g,
    const float* __restrict__ vg, unsigned long long* __restrict__ mask,
    const int* __restrict__ idxb, float* __restrict__ ctx, int t)
{
  const int b = blockIdx.x;
  __shared__ float qs[256], vs[256], us[64], ps[64];
  __shared__ unsigned long long ms;
  const int tid = threadIdx.x;
  qs[tid] = qg[(b << 8) + tid];
  vs[tid] = vg[tid];
  if (tid == 0) {
    unsigned long long m = mask[b];
    if (t > 0) {
      int s = idxb[b]; if (s < 0) s = 0;
      m |= (1ULL << s);
      if (m == ~0ULL) m &= ~(1ULL << 63);
      mask[b] = m;
    }
    ms = m;
  }
  __syncthreads();
  const unsigned long long mm = ms;
  const int w = tid >> 6, lane = tid & 63;
  const float* eb = e2g + ((size_t)b << 14);
  for (int li = 0; li < 16; ++li) {
    const int l = (w << 4) + li;
    const float* ep = eb + (l << 8);
    float s = 0.f;
#pragma unroll
    for (int j = 0; j < 4; ++j) {
      const int h = lane + (j << 6);
      s += vs[h] * ftanh(qs[h] + ep[h]);
    }
#pragma unroll
    for (int off = 32; off; off >>= 1) s += __shfl_xor(s, off, 64);
    if (lane == 0) us[l] = ((mm >> l) & 1ULL) ? NEGV : s;
  }
  __syncthreads();
  if (tid < 64) {
    const float xv = us[tid];
    float mx = xv;
#pragma unroll
    for (int off = 32; off; off >>= 1) mx = fmaxf(mx, __shfl_xor(mx, off, 64));
    const float ev = __expf(xv - mx);
    float sum = ev;
#pragma unroll
    for (int off = 32; off; off >>= 1) sum += __shfl_xor(sum, off, 64);
    ps[tid] = ev / sum;
  }
  __syncthreads();
  float a = 0.f;
#pragma unroll 16
  for (int l = 0; l < 64; ++l) a += eb[(l << 8) + tid] * ps[l];
  ctx[(b << 8) + tid] = a;
}

// ---------------------------------------------------------------------------
// attention-p: scores over e_p, 10*tanh, mask, log-softmax, argmax,
// output write (log_p + sel), embedding gather into x. 1 block per b.
// ---------------------------------------------------------------------------
__global__ __launch_bounds__(256) void attn_p_k(
    const float* __restrict__ qp, const float* __restrict__ e2p,
    const float* __restrict__ vp, const unsigned long long* __restrict__ mask,
    const float* __restrict__ emb, float* __restrict__ out_logp,
    float* __restrict__ out_sel, int* __restrict__ idxb,
    float* __restrict__ xb, int t)
{
  const int b = blockIdx.x;
  __shared__ float qs[256], vs[256], us[64];
  __shared__ int bsel;
  const int tid = threadIdx.x;
  qs[tid] = qp[(b << 8) + tid];
  vs[tid] = vp[tid];
  __syncthreads();
  const unsigned long long mm = mask[b];
  const int w = tid >> 6, lane = tid & 63;
  const float* eb = e2p + ((size_t)b << 14);
  for (int li = 0; li < 16; ++li) {
    const int l = (w << 4) + li;
    const float* ep = eb + (l << 8);
    float s = 0.f;
#pragma unroll
    for (int j = 0; j < 4; ++j) {
      const int h = lane + (j << 6);
      s += vs[h] * ftanh(qs[h] + ep[h]);
    }
#pragma unroll
    for (int off = 32; off; off >>= 1) s += __shfl_xor(s, off, 64);
    if (lane == 0) us[l] = ((mm >> l) & 1ULL) ? NEGV : 10.0f * ftanh(s);
  }
  __syncthreads();
  if (tid < 64) {
    const float xv = us[tid];
    float mx = xv;
#pragma unroll
    for (int off = 32; off; off >>= 1) mx = fmaxf(mx, __shfl_xor(mx, off, 64));
    const float sh = xv - mx;
    const float ev = __expf(sh);
    float sum = ev;
#pragma unroll
    for (int off = 32; off; off >>= 1) sum += __shfl_xor(sum, off, 64);
    const float lp = sh - __logf(sum);   // matches jax.nn.log_softmax form
    out_logp[((size_t)b << 12) + (t << 6) + tid] = lp;
    float bv = lp; int bi = tid;
#pragma unroll
    for (int off = 32; off; off >>= 1) {
      const float ov = __shfl_xor(bv, off, 64);
      const int   oi = __shfl_xor(bi, off, 64);
      if (ov > bv || (ov == bv && oi < bi)) { bv = ov; bi = oi; }
    }
    if (tid == 0) { idxb[b] = bi; out_sel[(b << 6) + t] = (float)bi; bsel = bi; }
  }
  __syncthreads();
  xb[(b << 8) + tid] = emb[((size_t)((bsel << 9) + b) << 8) + tid];
}

// ---------------------------------------------------------------------------
// setup kernels
// ---------------------------------------------------------------------------
__global__ __launch_bounds__(256) void init_k(
    const float* __restrict__ dec, const float* __restrict__ h0,
    const float* __restrict__ c0, float* __restrict__ xb,
    float* __restrict__ hb, float* __restrict__ cb,
    unsigned long long* __restrict__ mask, int* __restrict__ idxb)
{
  const int i = blockIdx.x * 256 + threadIdx.x;   // 131072 threads
  xb[i] = dec[i]; hb[i] = h0[i]; cb[i] = c0[i];
  if (i < 512) { mask[i] = 0ULL; idxb[i] = -1; }
}

// Wcat[n][k], n=4*j+p interleaved (p in {i,f,g,o}), k = [x-part | h-part]
__global__ __launch_bounds__(256) void prep_wcat_k(
    const float* __restrict__ Wih, const float* __restrict__ Whh,
    const float* __restrict__ bih, const float* __restrict__ bhh,
    float* __restrict__ Wcat, float* __restrict__ bcat)
{
  const int id = blockIdx.x * 256 + threadIdx.x;  // 524288 threads
  const int n = id >> 9, k = id & 511;
  const int r = ((n & 3) << 8) + (n >> 2);
  Wcat[id] = (k < 256) ? Wih[(r << 8) + k] : Whh[(r << 8) + (k - 256)];
  if (id < 1024) {
    const int rr = ((id & 3) << 8) + (id >> 2);
    bcat[id] = bih[rr] + bhh[rr];
  }
}

// Wfused = Wq_g @ Wm (256x320), bfused = Wq_g @ bm + bq_g
__global__ __launch_bounds__(256) void prep_wfused_k(
    const float* __restrict__ Wqg, const float* __restrict__ Wm,
    const float* __restrict__ bm, const float* __restrict__ bqg,
    float* __restrict__ Wf, float* __restrict__ bf)
{
  const int id = blockIdx.x * 256 + threadIdx.x;  // 81920 threads
  const int o = id / 320, j = id % 320;
  float acc = 0.f;
  for (int tt = 0; tt < 256; ++tt) acc += Wqg[(o << 8) + tt] * Wm[tt * 320 + j];
  Wf[id] = acc;
  if (id < 256) {
    float a2 = 0.f;
    for (int tt = 0; tt < 256; ++tt) a2 += Wqg[(id << 8) + tt] * bm[tt];
    bf[id] = a2 + bqg[id];
  }
}

// ---------------------------------------------------------------------------
extern "C" void kernel_launch(void* const* d_in, const int* in_sizes, int n_in,
                              void* d_out, int out_size, void* d_ws, size_t ws_size,
                              hipStream_t stream)
{
  const float* dec   = (const float*)d_in[0];
  const float* emb   = (const float*)d_in[1];
  const float* h0    = (const float*)d_in[2];
  const float* c0    = (const float*)d_in[3];
  const float* ctxin = (const float*)d_in[4];
  const float* cour  = (const float*)d_in[5];
  // d_in[6] = init_mask (all false) — initialized directly in init_k
  const float* Wih   = (const float*)d_in[7];
  const float* Whh   = (const float*)d_in[8];
  const float* bih   = (const float*)d_in[9];
  const float* bhh   = (const float*)d_in[10];
  const float* Wm    = (const float*)d_in[11];
  const float* bm    = (const float*)d_in[12];
  const float* Wqp   = (const float*)d_in[13];
  const float* bqp   = (const float*)d_in[14];
  const float* Wrp   = (const float*)d_in[15];
  const float* brp   = (const float*)d_in[16];
  const float* vp    = (const float*)d_in[17];
  const float* Wqg   = (const float*)d_in[18];
  const float* bqg   = (const float*)d_in[19];
  const float* Wrg   = (const float*)d_in[20];
  const float* brg   = (const float*)d_in[21];
  const float* vg    = (const float*)d_in[22];

  float* ws = (float*)d_ws;
  float* e2g  = ws + 0;          // [B][L][H] 8388608
  float* e2p  = ws + 8388608;    // 8388608
  float* Wcat = ws + 16777216;   // 524288
  float* bcat = ws + 17301504;   // 1024
  float* Wfg  = ws + 17302528;   // 81920
  float* bfg  = ws + 17384448;   // 256
  float* hb0  = ws + 17384704;   // 131072
  float* hb1  = ws + 17515776;   // 131072
  float* cb0  = ws + 17646848;   // 131072
  float* cb1  = ws + 17777920;   // 131072
  float* xb   = ws + 17908992;   // 131072
  float* qg   = ws + 18040064;   // 131072
  float* ctxb = ws + 18171136;   // 131072
  float* qp   = ws + 18302208;   // 131072
  unsigned long long* maskb = (unsigned long long*)(ws + 18433280); // 512 u64
  int* idxb   = (int*)(ws + 18434304);                              // 512 int

  float* out_logp = (float*)d_out;              // [B][64][64]
  float* out_sel  = (float*)d_out + 2097152;    // [B][64]

  // setup
  init_k<<<512, 256, 0, stream>>>(dec, h0, c0, xb, hb0, cb0, maskb, idxb);
  prep_wcat_k<<<2048, 256, 0, stream>>>(Wih, Whh, bih, bhh, Wcat, bcat);
  prep_wfused_k<<<320, 256, 0, stream>>>(Wqg, Wm, bm, bqg, Wfg, bfg);
  // e_g/e_p precompute: rows (b*64+l) read from context row (l*512+b)
  gemm_bias_k<<<dim3(4, 512), 256, 0, stream>>>(ctxin, nullptr, Wrg, brg, e2g,
                                                32768, 256, 256, 256, 0, 1);
  gemm_bias_k<<<dim3(4, 512), 256, 0, stream>>>(ctxin, nullptr, Wrp, brp, e2p,
                                                32768, 256, 256, 256, 0, 1);

  for (int t = 0; t < 64; ++t) {
    float* hcur = (t & 1) ? hb1 : hb0;
    float* hnew = (t & 1) ? hb0 : hb1;
    float* ccur = (t & 1) ? cb1 : cb0;
    float* cnew = (t & 1) ? cb0 : cb1;
    gates_lstm_k<<<dim3(16, 8), 256, 0, stream>>>(xb, hcur, Wcat, bcat,
                                                  ccur, cnew, hnew);
    gemm_bias_k<<<dim3(4, 8), 256, 0, stream>>>(hnew, cour, Wfg, bfg, qg,
                                                512, 256, 320, 256, 64, 0);
    attn_g_k<<<512, 256, 0, stream>>>(qg, e2g, vg, maskb, idxb, ctxb, t);
    gemm_bias_k<<<dim3(4, 8), 256, 0, stream>>>(ctxb, nullptr, Wqp, bqp, qp,
                                                512, 256, 256, 256, 0, 0);
    attn_p_k<<<512, 256, 0, stream>>>(qp, e2p, vp, maskb, emb,
                                      out_logp, out_sel, idxb, xb, t);
  }
}

// Round 2
// 3785.187 us; speedup vs baseline: 1.9429x; 1.9429x over previous
//
#include <hip/hip_runtime.h>
#include <cstdint>
#include <cstddef>

#define NEGV -1000000000.0f

// ---------- fast device math (fp32, argmax-safe) ----------
__device__ __forceinline__ float fsigm(float x) {
  return 1.0f / (1.0f + __expf(-x));
}
__device__ __forceinline__ float ftanh(float x) {
  x = fminf(x, 30.0f);
  const float e = __expf(2.0f * x);
  return (e - 1.0f) / (e + 1.0f);
}

// ---------------------------------------------------------------------------
// Generic fp32 GEMM (setup only): C[M,N] = A0 @ W[N,K]^T + bias
// permuteBL: A row m=(b*64+l) read from physical row (l*512+b) (context layout)
// BM=BN=64, BK=16, 256 threads, 4x4 micro-tile.
// ---------------------------------------------------------------------------
__global__ __launch_bounds__(256) void gemm_bias_k(
    const float* __restrict__ A0,
    const float* __restrict__ W, const float* __restrict__ bias,
    float* __restrict__ C, int N, int K, int permuteBL)
{
  __shared__ float As[16][68];
  __shared__ float Ws[16][68];
  const int bn = blockIdx.x << 6;
  const int bm = blockIdx.y << 6;
  const int t  = threadIdx.x;
  const int ty = t >> 4, tx = t & 15;
  const int lr = t >> 2, lk = (t & 3) << 2;
  const int m  = bm + lr;
  const size_t arow = permuteBL ? (size_t)(((m & 63) << 9) | (m >> 6)) : (size_t)m;
  const float* wrow = W + (size_t)(bn + lr) * K;
  float acc[4][4] = {};
  for (int k0 = 0; k0 < K; k0 += 16) {
    const int kk = k0 + lk;
    const float4 av = *(const float4*)(A0 + arow * (size_t)K + kk);
    const float4 wv = *(const float4*)(wrow + kk);
    As[lk + 0][lr] = av.x; As[lk + 1][lr] = av.y; As[lk + 2][lr] = av.z; As[lk + 3][lr] = av.w;
    Ws[lk + 0][lr] = wv.x; Ws[lk + 1][lr] = wv.y; Ws[lk + 2][lr] = wv.z; Ws[lk + 3][lr] = wv.w;
    __syncthreads();
#pragma unroll
    for (int k = 0; k < 16; ++k) {
      const float4 a = *(const float4*)&As[k][ty << 2];
      const float4 w = *(const float4*)&Ws[k][tx << 2];
      acc[0][0] += a.x * w.x; acc[0][1] += a.x * w.y; acc[0][2] += a.x * w.z; acc[0][3] += a.x * w.w;
      acc[1][0] += a.y * w.x; acc[1][1] += a.y * w.y; acc[1][2] += a.y * w.z; acc[1][3] += a.y * w.w;
      acc[2][0] += a.z * w.x; acc[2][1] += a.z * w.y; acc[2][2] += a.z * w.z; acc[2][3] += a.z * w.w;
      acc[3][0] += a.w * w.x; acc[3][1] += a.w * w.y; acc[3][2] += a.w * w.z; acc[3][3] += a.w * w.w;
    }
    __syncthreads();
  }
  const float4 bv = *(const float4*)(bias + bn + (tx << 2));
#pragma unroll
  for (int i = 0; i < 4; ++i) {
    float4 o;
    o.x = acc[i][0] + bv.x; o.y = acc[i][1] + bv.y;
    o.z = acc[i][2] + bv.z; o.w = acc[i][3] + bv.w;
    *(float4*)(C + (size_t)(bm + (ty << 2) + i) * N + bn + (tx << 2)) = o;
  }
}

// ---------------------------------------------------------------------------
// gates GEMM (M=512, N=1024 interleaved i,f,g,o per unit, K=512 = [x|h])
// + fused LSTM epilogue. BM=16, BN=64, BK=32 -> 512 blocks (2/CU).
// ---------------------------------------------------------------------------
__global__ __launch_bounds__(256) void gates_lstm_k(
    const float* __restrict__ x, const float* __restrict__ hin,
    const float* __restrict__ Wcat, const float* __restrict__ bcat,
    const float* __restrict__ cin, float* __restrict__ cnew,
    float* __restrict__ hnew)
{
  __shared__ __align__(16) float As[16][36];   // [m][k]
  __shared__ __align__(16) float Ws[32][68];   // [k][n]
  const int bn = blockIdx.x << 6;
  const int bm = blockIdx.y << 4;
  const int t  = threadIdx.x;
  const int ty = t >> 4, tx = t & 15;
  const int ar = t >> 4, ak = (t & 15) << 1;   // A staging: one float2
  const int wr = t >> 2, wk = (t & 3) << 3;    // W staging: two float4
  const float* wrow = Wcat + ((size_t)(bn + wr) << 9);
  const int arow = bm + ar;
  float acc0 = 0.f, acc1 = 0.f, acc2 = 0.f, acc3 = 0.f;
  for (int k0 = 0; k0 < 512; k0 += 32) {
    const int kk = k0 + ak;
    float2 av;
    if (kk < 256) av = *(const float2*)(x   + ((size_t)arow << 8) + kk);
    else          av = *(const float2*)(hin + ((size_t)arow << 8) + (kk - 256));
    const float4 w0 = *(const float4*)(wrow + k0 + wk);
    const float4 w1 = *(const float4*)(wrow + k0 + wk + 4);
    *(float2*)&As[ar][ak] = av;
    Ws[wk + 0][wr] = w0.x; Ws[wk + 1][wr] = w0.y; Ws[wk + 2][wr] = w0.z; Ws[wk + 3][wr] = w0.w;
    Ws[wk + 4][wr] = w1.x; Ws[wk + 5][wr] = w1.y; Ws[wk + 6][wr] = w1.z; Ws[wk + 7][wr] = w1.w;
    __syncthreads();
#pragma unroll
    for (int k = 0; k < 32; ++k) {
      const float a  = As[ty][k];
      const float4 w = *(const float4*)&Ws[k][tx << 2];
      acc0 += a * w.x; acc1 += a * w.y; acc2 += a * w.z; acc3 += a * w.w;
    }
    __syncthreads();
  }
  const float4 bb = *(const float4*)(bcat + bn + (tx << 2));
  const int jc = (bn >> 2) + tx;
  const int m  = bm + ty;
  const float ig = fsigm(acc0 + bb.x);
  const float fg = fsigm(acc1 + bb.y);
  const float gg = ftanh(acc2 + bb.z);
  const float og = fsigm(acc3 + bb.w);
  const float c  = fg * cin[(m << 8) + jc] + ig * gg;
  const float h  = og * ftanh(c);
  cnew[(m << 8) + jc] = c;
  hnew[(m << 8) + jc] = h;
}

// ---------------------------------------------------------------------------
// Fused per-step attention: mask update, qg matvec, scores_g, softmax,
// qp accumulation (via precomputed Eg2), scores_p, log-softmax, argmax,
// output write, embedding gather. One block per batch row b.
// ---------------------------------------------------------------------------
__global__ __launch_bounds__(256) void step_attn_k(
    const float* __restrict__ h, const float* __restrict__ e2g,
    const float* __restrict__ e2p, const float* __restrict__ Eg2,
    const float* __restrict__ Wq1T4, const float* __restrict__ qcour,
    const float* __restrict__ vg, const float* __restrict__ vp,
    unsigned long long* __restrict__ mask, int* __restrict__ idxb,
    const float* __restrict__ emb, float* __restrict__ out_logp,
    float* __restrict__ out_sel, float* __restrict__ xb, int t)
{
  const int b = blockIdx.x, tid = threadIdx.x;
  __shared__ __align__(16) float hs[256], qgs[256], qps[256], vgs[256], vps[256];
  __shared__ float us[64], ps[64];
  __shared__ unsigned long long ms;
  __shared__ int bsel;
  hs[tid]  = h[(b << 8) + tid];
  vgs[tid] = vg[tid];
  vps[tid] = vp[tid];
  if (tid == 0) {
    unsigned long long m = mask[b];
    if (t > 0) {
      int s = idxb[b]; if (s < 0) s = 0;
      m |= (1ULL << s);
      if (m == ~0ULL) m &= ~(1ULL << 63);
      mask[b] = m;
    }
    ms = m;
  }
  __syncthreads();
  const unsigned long long mm = ms;
  const int w = tid >> 6, lane = tid & 63;

  // phase 0: qg[tid] = qcour[b,tid] + sum_k Wq1[tid][k] * h[b,k]
  {
    float acc = qcour[(b << 8) + tid];
    const float4* wp = (const float4*)Wq1T4 + tid;
#pragma unroll 8
    for (int kc = 0; kc < 64; ++kc) {
      const float4 wv = wp[kc << 8];
      const float4 h4 = *(const float4*)&hs[kc << 2];
      acc += wv.x * h4.x + wv.y * h4.y + wv.z * h4.z + wv.w * h4.w;
    }
    qgs[tid] = acc;
  }
  __syncthreads();

  // scores_g over e2g[b]
  {
    const float* eb = e2g + ((size_t)b << 14);
    const float4 q4 = *(const float4*)&qgs[lane << 2];
    const float4 v4 = *(const float4*)&vgs[lane << 2];
    for (int li = 0; li < 16; ++li) {
      const int l = (w << 4) + li;
      const float4 e4 = *(const float4*)(eb + (l << 8) + (lane << 2));
      float s = v4.x * ftanh(q4.x + e4.x) + v4.y * ftanh(q4.y + e4.y)
              + v4.z * ftanh(q4.z + e4.z) + v4.w * ftanh(q4.w + e4.w);
#pragma unroll
      for (int off = 32; off; off >>= 1) s += __shfl_xor(s, off, 64);
      if (lane == 0) us[l] = ((mm >> l) & 1ULL) ? NEGV : s;
    }
  }
  __syncthreads();
  if (tid < 64) {
    const float xv = us[tid];
    float mx = xv;
#pragma unroll
    for (int off = 32; off; off >>= 1) mx = fmaxf(mx, __shfl_xor(mx, off, 64));
    const float ev = __expf(xv - mx);
    float sum = ev;
#pragma unroll
    for (int off = 32; off; off >>= 1) sum += __shfl_xor(sum, off, 64);
    ps[tid] = ev / sum;
  }
  __syncthreads();

  // qp[tid] = sum_l p[l] * Eg2[b,l,tid]   (bias pre-folded into Eg2)
  {
    float aq = 0.f;
    const float* ec = Eg2 + ((size_t)b << 14) + tid;
#pragma unroll 8
    for (int l = 0; l < 64; ++l) aq += ps[l] * ec[l << 8];
    qps[tid] = aq;
  }
  __syncthreads();

  // scores_p over e2p[b], 10*tanh, mask, log-softmax, argmax, outputs
  {
    const float* eb = e2p + ((size_t)b << 14);
    const float4 q4 = *(const float4*)&qps[lane << 2];
    const float4 v4 = *(const float4*)&vps[lane << 2];
    for (int li = 0; li < 16; ++li) {
      const int l = (w << 4) + li;
      const float4 e4 = *(const float4*)(eb + (l << 8) + (lane << 2));
      float s = v4.x * ftanh(q4.x + e4.x) + v4.y * ftanh(q4.y + e4.y)
              + v4.z * ftanh(q4.z + e4.z) + v4.w * ftanh(q4.w + e4.w);
#pragma unroll
      for (int off = 32; off; off >>= 1) s += __shfl_xor(s, off, 64);
      if (lane == 0) us[l] = ((mm >> l) & 1ULL) ? NEGV : 10.0f * ftanh(s);
    }
  }
  __syncthreads();
  if (tid < 64) {
    const float xv = us[tid];
    float mx = xv;
#pragma unroll
    for (int off = 32; off; off >>= 1) mx = fmaxf(mx, __shfl_xor(mx, off, 64));
    const float sh = xv - mx;
    const float ev = __expf(sh);
    float sum = ev;
#pragma unroll
    for (int off = 32; off; off >>= 1) sum += __shfl_xor(sum, off, 64);
    const float lp = sh - __logf(sum);
    out_logp[((size_t)b << 12) + (t << 6) + tid] = lp;
    float bv = lp; int bi = tid;
#pragma unroll
    for (int off = 32; off; off >>= 1) {
      const float ov = __shfl_xor(bv, off, 64);
      const int   oi = __shfl_xor(bi, off, 64);
      if (ov > bv || (ov == bv && oi < bi)) { bv = ov; bi = oi; }
    }
    if (tid == 0) { idxb[b] = bi; out_sel[(b << 6) + t] = (float)bi; bsel = bi; }
  }
  __syncthreads();
  xb[(b << 8) + tid] = emb[(((size_t)(bsel << 9) + b) << 8) + tid];
}

// ---------------------------------------------------------------------------
// setup kernels
// ---------------------------------------------------------------------------
__global__ __launch_bounds__(256) void init_k(
    const float* __restrict__ dec, const float* __restrict__ h0,
    const float* __restrict__ c0, float* __restrict__ xb,
    float* __restrict__ hb, float* __restrict__ cb,
    unsigned long long* __restrict__ mask, int* __restrict__ idxb)
{
  const int i = blockIdx.x * 256 + threadIdx.x;
  xb[i] = dec[i]; hb[i] = h0[i]; cb[i] = c0[i];
  if (i < 512) { mask[i] = 0ULL; idxb[i] = -1; }
}

// Wcat[n][k], n=4*j+p interleaved (p in {i,f,g,o}), k = [x-part | h-part]
__global__ __launch_bounds__(256) void prep_wcat_k(
    const float* __restrict__ Wih, const float* __restrict__ Whh,
    const float* __restrict__ bih, const float* __restrict__ bhh,
    float* __restrict__ Wcat, float* __restrict__ bcat)
{
  const int id = blockIdx.x * 256 + threadIdx.x;
  const int n = id >> 9, k = id & 511;
  const int r = ((n & 3) << 8) + (n >> 2);
  Wcat[id] = (k < 256) ? Wih[(r << 8) + k] : Whh[(r << 8) + (k - 256)];
  if (id < 1024) {
    const int rr = ((id & 3) << 8) + (id >> 2);
    bcat[id] = bih[rr] + bhh[rr];
  }
}

// Wfused = Wq_g @ Wm (256x320), bfused = Wq_g @ bm + bq_g
__global__ __launch_bounds__(256) void prep_wfused_k(
    const float* __restrict__ Wqg, const float* __restrict__ Wm,
    const float* __restrict__ bm, const float* __restrict__ bqg,
    float* __restrict__ Wf, float* __restrict__ bf)
{
  const int id = blockIdx.x * 256 + threadIdx.x;  // 81920
  const int o = id / 320, j = id % 320;
  float acc = 0.f;
  for (int tt = 0; tt < 256; ++tt) acc += Wqg[(o << 8) + tt] * Wm[tt * 320 + j];
  Wf[id] = acc;
  if (id < 256) {
    float a2 = 0.f;
    for (int tt = 0; tt < 256; ++tt) a2 += Wqg[(id << 8) + tt] * bm[tt];
    bf[id] = a2 + bqg[id];
  }
}

// Wq1T4: packed transpose of Wfused[:, :256] for float4 matvec reads.
__global__ __launch_bounds__(256) void prep_wq1t4_k(
    const float* __restrict__ Wf, float* __restrict__ Wq1T4)
{
  const int id = blockIdx.x * 256 + threadIdx.x;  // 65536
  const int k = id >> 8, o = id & 255;
  Wq1T4[((k >> 2) << 10) + (o << 2) + (k & 3)] = Wf[o * 320 + k];
}

// qcour[b,o] = bfused[o] + sum_{k<64} Wfused[o][256+k] * cour[b][k]
__global__ __launch_bounds__(256) void prep_qcour_k(
    const float* __restrict__ Wf, const float* __restrict__ bf,
    const float* __restrict__ cour, float* __restrict__ qcour)
{
  const int b = blockIdx.x, o = threadIdx.x;
  __shared__ float cs[64];
  if (o < 64) cs[o] = cour[(b << 6) + o];
  __syncthreads();
  float acc = bf[o];
#pragma unroll 8
  for (int k = 0; k < 64; ++k) acc += Wf[o * 320 + 256 + k] * cs[k];
  qcour[(b << 8) + o] = acc;
}

// Wgp = Wqp @ Wrg (256x256)
__global__ __launch_bounds__(256) void prep_wgp_k(
    const float* __restrict__ Wqp, const float* __restrict__ Wrg,
    float* __restrict__ Wgp)
{
  const int o = blockIdx.x, k = threadIdx.x;
  float acc = 0.f;
#pragma unroll 8
  for (int tt = 0; tt < 256; ++tt) acc += Wqp[(o << 8) + tt] * Wrg[(tt << 8) + k];
  Wgp[(o << 8) + k] = acc;
}

// bgp = Wqp @ brg + bqp
__global__ __launch_bounds__(256) void prep_bgp_k(
    const float* __restrict__ Wqp, const float* __restrict__ brg,
    const float* __restrict__ bqp, float* __restrict__ bgp)
{
  const int o = threadIdx.x;
  float acc = bqp[o];
  for (int tt = 0; tt < 256; ++tt) acc += Wqp[(o << 8) + tt] * brg[tt];
  bgp[o] = acc;
}

// ---------------------------------------------------------------------------
extern "C" void kernel_launch(void* const* d_in, const int* in_sizes, int n_in,
                              void* d_out, int out_size, void* d_ws, size_t ws_size,
                              hipStream_t stream)
{
  const float* dec   = (const float*)d_in[0];
  const float* emb   = (const float*)d_in[1];
  const float* h0    = (const float*)d_in[2];
  const float* c0    = (const float*)d_in[3];
  const float* ctxin = (const float*)d_in[4];
  const float* cour  = (const float*)d_in[5];
  const float* Wih   = (const float*)d_in[7];
  const float* Whh   = (const float*)d_in[8];
  const float* bih   = (const float*)d_in[9];
  const float* bhh   = (const float*)d_in[10];
  const float* Wm    = (const float*)d_in[11];
  const float* bm    = (const float*)d_in[12];
  const float* Wqp   = (const float*)d_in[13];
  const float* bqp   = (const float*)d_in[14];
  const float* Wrp   = (const float*)d_in[15];
  const float* brp   = (const float*)d_in[16];
  const float* vp    = (const float*)d_in[17];
  const float* Wqg   = (const float*)d_in[18];
  const float* bqg   = (const float*)d_in[19];
  const float* Wrg   = (const float*)d_in[20];
  const float* brg   = (const float*)d_in[21];
  const float* vg    = (const float*)d_in[22];

  float* ws = (float*)d_ws;
  float* e2g    = ws + 0;         // 8388608
  float* e2p    = ws + 8388608;   // 8388608
  float* Eg2    = ws + 16777216;  // 8388608
  float* Wcat   = ws + 25165824;  // 524288
  float* bcat   = ws + 25690112;  // 1024
  float* Wfused = ws + 25691136;  // 81920
  float* bfused = ws + 25773056;  // 256
  float* Wq1T4  = ws + 25773312;  // 65536
  float* qcour  = ws + 25838848;  // 131072
  float* Wgp    = ws + 25969920;  // 65536
  float* bgp    = ws + 26035456;  // 256
  float* hb0    = ws + 26035712;  // 131072
  float* hb1    = ws + 26166784;  // 131072
  float* cb0    = ws + 26297856;  // 131072
  float* cb1    = ws + 26428928;  // 131072
  float* xb     = ws + 26560000;  // 131072
  unsigned long long* maskb = (unsigned long long*)(ws + 26691072); // 512 u64
  int* idxb     = (int*)(ws + 26692096);                            // 512

  float* out_logp = (float*)d_out;            // [B][64][64]
  float* out_sel  = (float*)d_out + 2097152;  // [B][64]

  // ---- setup ----
  init_k<<<512, 256, 0, stream>>>(dec, h0, c0, xb, hb0, cb0, maskb, idxb);
  prep_wcat_k<<<2048, 256, 0, stream>>>(Wih, Whh, bih, bhh, Wcat, bcat);
  prep_wfused_k<<<320, 256, 0, stream>>>(Wqg, Wm, bm, bqg, Wfused, bfused);
  prep_wq1t4_k<<<256, 256, 0, stream>>>(Wfused, Wq1T4);
  prep_qcour_k<<<512, 256, 0, stream>>>(Wfused, bfused, cour, qcour);
  prep_wgp_k<<<256, 256, 0, stream>>>(Wqp, Wrg, Wgp);
  prep_bgp_k<<<1, 256, 0, stream>>>(Wqp, brg, bqp, bgp);
  gemm_bias_k<<<dim3(4, 512), 256, 0, stream>>>(ctxin, Wrg, brg, e2g, 256, 256, 1);
  gemm_bias_k<<<dim3(4, 512), 256, 0, stream>>>(ctxin, Wrp, brp, e2p, 256, 256, 1);
  gemm_bias_k<<<dim3(4, 512), 256, 0, stream>>>(ctxin, Wgp, bgp, Eg2, 256, 256, 1);

  // ---- 64 sequential steps, 2 kernels each ----
  for (int t = 0; t < 64; ++t) {
    float* hcur = (t & 1) ? hb1 : hb0;
    float* hnew = (t & 1) ? hb0 : hb1;
    float* ccur = (t & 1) ? cb1 : cb0;
    float* cnew = (t & 1) ? cb0 : cb1;
    gates_lstm_k<<<dim3(16, 32), 256, 0, stream>>>(xb, hcur, Wcat, bcat,
                                                   ccur, cnew, hnew);
    step_attn_k<<<512, 256, 0, stream>>>(hnew, e2g, e2p, Eg2, Wq1T4, qcour,
                                         vg, vp, maskb, idxb, emb,
                                         out_logp, out_sel, xb, t);
  }
}